// Round 16
// baseline (179.088 us; speedup 1.0000x reference)
//
#include <hip/hip_runtime.h>

#define NN 50000
#define NE 800000
#define FIN 512
#define FHID 256
#define FOUT 128
#define MPAD 50048  // 782 * 64

#define TW1_BLOCKS  512     // FIN*FHID/256
#define TW2_BLOCKS  128     // FHID*FOUT/256

// Two-level bucket sort
#define NBKT   196          // coarse bucket = dst >> 8
#define BCAP   5120         // slots/bucket: mean 4082 + 16 sigma
#define BSTRIDE 16          // bcur counter stride (ints) -> one 64B line each
#define PA_BLOCKS 392
#define E_CHA    2048       // 392 * 2048 = 802816 >= NE
#define PB_BLOCKS 196

using bf16x8 = __attribute__((ext_vector_type(8))) short;
using f32x4  = __attribute__((ext_vector_type(4))) float;
using u16x8  = __attribute__((ext_vector_type(8))) unsigned short;

__device__ __forceinline__ unsigned short f2bf(float f) {
    unsigned int u = __builtin_bit_cast(unsigned int, f);
    unsigned int r = (u + 0x7FFFu + ((u >> 16) & 1u)) >> 16;   // RNE
    return (unsigned short)r;
}
__device__ __forceinline__ float bf2f(unsigned short u) {
    return __builtin_bit_cast(float, (unsigned int)u << 16);
}
__device__ __forceinline__ void gload_lds16(const void* g, void* l) {
    __builtin_amdgcn_global_load_lds(
        (const __attribute__((address_space(1))) void*)g,
        (__attribute__((address_space(3))) void*)l, 16, 0, 0);
}

// ---- k1: passA (bucket bin) || transpose W1 || transpose W2 ----

__global__ __launch_bounds__(256) void fused_passa_prep_kernel(
    const int* __restrict__ src, const int* __restrict__ dst,
    const float* __restrict__ w, int* __restrict__ bcur, int2* __restrict__ barr,
    const float* __restrict__ W1, unsigned short* __restrict__ W1T,
    const float* __restrict__ W2, unsigned short* __restrict__ W2T) {
    int b = blockIdx.x, tid = threadIdx.x;
    if (b < PA_BLOCKS) {
        __shared__ int hist[NBKT];
        __shared__ int resv[NBKT];
        if (tid < NBKT) hist[tid] = 0;
        __syncthreads();
        int base = b * E_CHA + tid;
        int  d[8];
        bool m[8];
#pragma unroll
        for (int j = 0; j < 8; ++j) {
            int e = base + j * 256;
            m[j] = e < NE;
            d[j] = m[j] ? dst[e] : 0;
        }
#pragma unroll
        for (int j = 0; j < 8; ++j)
            if (m[j]) atomicAdd(&hist[d[j] >> 8], 1);
        __syncthreads();
        if (tid < NBKT) {
            int h = hist[tid];
            resv[tid] = (h > 0) ? atomicAdd(&bcur[tid * BSTRIDE], h) : 0;
            hist[tid] = 0;  // reuse as rank counter
        }
        __syncthreads();
        int   s[8];
        float wv[8];
#pragma unroll
        for (int j = 0; j < 8; ++j) {
            int e = base + j * 256;
            s[j]  = m[j] ? src[e] : 0;
            wv[j] = m[j] ? w[e] : 0.f;
        }
#pragma unroll
        for (int j = 0; j < 8; ++j) {
            if (m[j]) {
                int bb = d[j] >> 8;
                int r  = atomicAdd(&hist[bb], 1);
                int pos = resv[bb] + r;
                if (pos < BCAP)
                    barr[(size_t)bb * BCAP + pos] =
                        make_int2(s[j] | ((d[j] & 255) << 16), __float_as_int(wv[j]));
            }
        }
    } else if (b < PA_BLOCKS + TW1_BLOCKS) {
        int t = (b - PA_BLOCKS) * 256 + tid;
        int n = t % FHID, k = t / FHID;
        W1T[(size_t)n * FIN + k] = f2bf(W1[t]);
    } else {
        int t = (b - PA_BLOCKS - TW1_BLOCKS) * 256 + tid;
        int n = t % FOUT, k = t / FOUT;
        W2T[(size_t)n * FHID + k] = f2bf(W2[t]);
    }
}

// ---- GEMM1 body: 64x256 full-N tile, BK=64, direct f32 A (r14, unchanged) ----

__device__ __forceinline__ void gemm1_body(const float* __restrict__ X,
                                           const unsigned short* __restrict__ BT,
                                           unsigned short* __restrict__ C,
                                           int bx) {
    __shared__ unsigned short As[64 * 64];    // 8 KB
    __shared__ unsigned short Bs[256 * 64];   // 32 KB

    const int tid  = threadIdx.x;
    const int lane = tid & 63;
    const int wid  = tid >> 6;
    const int brow = bx * 64;
    const int r15   = lane & 15;
    const int khalf = (lane >> 4) * 8;

    const int arow0 = tid >> 3;
    const int arow1 = 32 + (tid >> 3);
    const int acol  = (tid & 7) * 8;
    const int g0 = min(brow + arow0, NN - 1);
    const int g1 = min(brow + arow1, NN - 1);
    const float4* ap0 = (const float4*)(X + (size_t)g0 * FIN + acol);
    const float4* ap1 = (const float4*)(X + (size_t)g1 * FIN + acol);
    const int ab0 = arow0 * 128 + ((acol * 2) ^ ((arow0 & 7) << 4));
    const int ab1 = arow1 * 128 + ((acol * 2) ^ ((arow1 & 7) << 4));

    f32x4 acc[4][4] = {};
    float4 a00 = ap0[0], a01 = ap0[1], a10 = ap1[0], a11 = ap1[1];

#pragma unroll
    for (int k = 0; k < 8; ++k) {
        const int k0 = k * 64;
#pragma unroll
        for (int c = 0; c < 8; ++c) {
            int b   = wid * 8192 + c * 1024 + lane * 16;
            int row = b >> 7;
            int cby = (b & 127) ^ ((row & 7) << 4);
            const char* gb = (const char*)(BT + (size_t)row * FIN + k0) + cby;
            gload_lds16(gb, (char*)Bs + wid * 8192 + c * 1024);
        }
        {
            u16x8 v;
            v[0] = f2bf(a00.x); v[1] = f2bf(a00.y); v[2] = f2bf(a00.z); v[3] = f2bf(a00.w);
            v[4] = f2bf(a01.x); v[5] = f2bf(a01.y); v[6] = f2bf(a01.z); v[7] = f2bf(a01.w);
            *(u16x8*)((char*)As + ab0) = v;
            v[0] = f2bf(a10.x); v[1] = f2bf(a10.y); v[2] = f2bf(a10.z); v[3] = f2bf(a10.w);
            v[4] = f2bf(a11.x); v[5] = f2bf(a11.y); v[6] = f2bf(a11.z); v[7] = f2bf(a11.w);
            *(u16x8*)((char*)As + ab1) = v;
        }
        __syncthreads();

        if (k < 7) {
            int q = (k0 + 64) >> 2;
            a00 = ap0[q]; a01 = ap0[q + 1]; a10 = ap1[q]; a11 = ap1[q + 1];
        }

        bf16x8 bfr[4][2];
#pragma unroll
        for (int n = 0; n < 4; ++n) {
            int row = wid * 64 + n * 16 + r15;
            int rb  = row * 128;
            int sw  = (row & 7) << 4;
#pragma unroll
            for (int ks = 0; ks < 2; ++ks)
                bfr[n][ks] = *(const bf16x8*)((const char*)Bs + rb + (((ks * 32 + khalf) * 2) ^ sw));
        }
#pragma unroll
        for (int m = 0; m < 4; ++m) {
            int row = m * 16 + r15;
            int rb  = row * 128;
            int sw  = (row & 7) << 4;
            bf16x8 af0 = *(const bf16x8*)((const char*)As + rb + (((0 + khalf) * 2) ^ sw));
            bf16x8 af1 = *(const bf16x8*)((const char*)As + rb + (((32 + khalf) * 2) ^ sw));
#pragma unroll
            for (int n = 0; n < 4; ++n) {
                acc[m][n] = __builtin_amdgcn_mfma_f32_16x16x32_bf16(af0, bfr[n][0], acc[m][n], 0, 0, 0);
                acc[m][n] = __builtin_amdgcn_mfma_f32_16x16x32_bf16(af1, bfr[n][1], acc[m][n], 0, 0, 0);
            }
        }
        __syncthreads();
    }

    const int rsub = (lane >> 4) * 4;
#pragma unroll
    for (int m = 0; m < 4; ++m) {
#pragma unroll
        for (int r = 0; r < 4; ++r) {
            int grow = brow + m * 16 + rsub + r;
            if (grow < NN) {
#pragma unroll
                for (int n = 0; n < 4; ++n)
                    C[(size_t)grow * FHID + wid * 64 + n * 16 + r15] = f2bf(acc[m][n][r]);
            }
        }
    }
}

// ---- passB body (self-scan, unchanged) ----

__device__ __forceinline__ void passb_body(const int2* __restrict__ barr,
                                           const int* __restrict__ bcur,
                                           int* __restrict__ off,
                                           int2* __restrict__ csr) {
    __shared__ int sc[256];
    __shared__ int cnt[256];
    __shared__ int pre[256];
    __shared__ int wsum[4];
    int b = blockIdx.x, tid = threadIdx.x, lane = tid & 63, wid = tid >> 6;

    int v = (tid < NBKT) ? min(bcur[tid * BSTRIDE], BCAP) : 0;
    int s = v;
#pragma unroll
    for (int d = 1; d < 64; d <<= 1) {
        int t = __shfl_up(s, d, 64);
        if (lane >= d) s += t;
    }
    if (lane == 63) wsum[wid] = s;
    __syncthreads();
    int wo = 0;
#pragma unroll
    for (int j = 0; j < 4; ++j)
        if (j < wid) wo += wsum[j];
    sc[tid] = wo + s - v;
    if (b == 0 && tid == NBKT - 1) off[NN] = wo + s;
    cnt[tid] = 0;
    __syncthreads();

    int bko_b = sc[b];
    int total = min(bcur[b * BSTRIDE], BCAP);
    const int2* seg = barr + (size_t)b * BCAP;

    for (int k = tid; k < total; k += 256)
        atomicAdd(&cnt[(seg[k].x >> 16) & 255], 1);
    __syncthreads();
    int v2 = cnt[tid];
    int s2 = v2;
#pragma unroll
    for (int d = 1; d < 64; d <<= 1) {
        int t = __shfl_up(s2, d, 64);
        if (lane >= d) s2 += t;
    }
    if (lane == 63) wsum[wid] = s2;
    __syncthreads();
    int wo2 = 0;
#pragma unroll
    for (int j = 0; j < 4; ++j)
        if (j < wid) wo2 += wsum[j];
    int base = bko_b + wo2 + s2 - v2;
    pre[tid] = base;
    int n = b * 256 + tid;
    if (n < NN) off[n] = base;
    cnt[tid] = 0;
    __syncthreads();
    for (int k = tid; k < total; k += 256) {
        int2 pl = seg[k];
        int dlow = (pl.x >> 16) & 255;
        int r = atomicAdd(&cnt[dlow], 1);
        csr[pre[dlow] + r] = make_int2(pl.x & 0xFFFF, pl.y);
    }
}

// ---- k2: passB || gemm1 ----

__global__ __launch_bounds__(256) void fused_passb_gemm1_kernel(
    const int2* __restrict__ barr, const int* __restrict__ bcur,
    int* __restrict__ off, int2* __restrict__ csr,
    const float* __restrict__ X, const unsigned short* __restrict__ BT,
    unsigned short* __restrict__ C) {
    if (blockIdx.x < PB_BLOCKS) {
        passb_body(barr, bcur, off, csr);
    } else {
        gemm1_body(X, BT, C, blockIdx.x - PB_BLOCKS);
    }
}

// ---- k3': FUSED spmm1+gemm2 at 1024 threads (16 waves). Phase 1: each wave
// aggregates 4 nodes (2 per 32-lane half x 2 iters) into a swizzled LDS hidden
// tile — same math/order as the split spmm_pair. Phase 2: 16 waves split the
// 64x128 MFMA output (wave w: col-tile w>>1, m-pair (w&1)*2), B-fragments
// straight from L2-resident W2T. Saves the 51 MB Hb round-trip. ----

__global__ __launch_bounds__(1024) void fused_spmm1_gemm2_kernel(
    const unsigned short* __restrict__ H0,   // [MPAD][256] bf16
    const int* __restrict__ off, const int2* __restrict__ csr,
    const unsigned short* __restrict__ W2T,  // [128][256] bf16
    unsigned short* __restrict__ H1) {       // [MPAD][128] bf16
    __shared__ unsigned short hid[4 * 64 * 64];   // 4 K-panels of [64][64], swizzled (32 KB)

    const int tid  = threadIdx.x;
    const int lane = tid & 63;
    const int wv   = tid >> 6;            // 0..15
    const int brow = blockIdx.x * 64;

    // ---- phase 1: aggregate; wave handles rows wv*4 + {0..3} ----
    const int half  = lane >> 5;
    const int hl    = lane & 31;          // feature group: cols hl*8..+7
    const int panel = hl >> 3;
    const int pcolb = (hl & 7) * 16;
#pragma unroll
    for (int j = 0; j < 2; ++j) {
        int row = wv * 4 + j * 2 + half;      // 0..63
        int n   = brow + row;
        float acc[8] = {};
        if (n < NN) {
            int e0 = off[n], e1 = off[n + 1];
            for (int e = e0; e < e1; e += 8) {
                unsigned ssb[8];
                float    ww[8];
#pragma unroll
                for (int q = 0; q < 8; ++q) {
                    int  ee = e + q;
                    bool v  = ee < e1;
                    int2 sw = csr[v ? ee : e0];
                    ssb[q] = (unsigned)(sw.x * (FHID * 2));   // 32-bit byte offset
                    ww[q]  = v ? __int_as_float(sw.y) : 0.f;
                }
                u16x8 r[8];
#pragma unroll
                for (int q = 0; q < 8; ++q)
                    r[q] = *(const u16x8*)((const char*)H0 + ssb[q] + hl * 16);
#pragma unroll
                for (int q = 0; q < 8; ++q)
#pragma unroll
                    for (int kk = 0; kk < 8; ++kk)
                        acc[kk] += ww[q] * bf2f(r[q][kk]);
            }
        }
        u16x8 o;
#pragma unroll
        for (int kk = 0; kk < 8; ++kk) o[kk] = f2bf(fmaxf(acc[kk], 0.f));
        int byte = panel * 8192 + row * 128 + (pcolb ^ ((row & 7) << 4));
        *(u16x8*)((char*)hid + byte) = o;
    }
    __syncthreads();

    // ---- phase 2: wave w -> col-tile c = w>>1 (cols c*16..+15), m-tiles mb,mb+1 ----
    const int r15   = lane & 15;
    const int khalf = (lane >> 4) * 8;
    const int c   = wv >> 1;
    const int mb  = (wv & 1) * 2;
    f32x4 acc2[2] = {};
#pragma unroll
    for (int k = 0; k < 4; ++k) {
        bf16x8 bfr[2];
        {
            int wrow = c * 16 + r15;
#pragma unroll
            for (int ks = 0; ks < 2; ++ks)
                bfr[ks] = *(const bf16x8*)(W2T + (size_t)wrow * FHID + k * 64 + ks * 32 + khalf);
        }
#pragma unroll
        for (int m = 0; m < 2; ++m) {
            int row = (mb + m) * 16 + r15;
            int rb  = k * 8192 + row * 128;
            int sw  = (row & 7) << 4;
            bf16x8 af0 = *(const bf16x8*)((const char*)hid + rb + (((0  + khalf) * 2) ^ sw));
            bf16x8 af1 = *(const bf16x8*)((const char*)hid + rb + (((32 + khalf) * 2) ^ sw));
            acc2[m] = __builtin_amdgcn_mfma_f32_16x16x32_bf16(af0, bfr[0], acc2[m], 0, 0, 0);
            acc2[m] = __builtin_amdgcn_mfma_f32_16x16x32_bf16(af1, bfr[1], acc2[m], 0, 0, 0);
        }
    }
    const int rsub = (lane >> 4) * 4;
#pragma unroll
    for (int m = 0; m < 2; ++m) {
#pragma unroll
        for (int r = 0; r < 4; ++r) {
            int grow = brow + (mb + m) * 16 + rsub + r;
            if (grow < NN)
                H1[(size_t)grow * FOUT + c * 16 + r15] = f2bf(acc2[m][r]);
        }
    }
}

// ---- k4: pull-SpMM layer 2: 4 nodes per wave (16-lane quarters), f32 out ----

__global__ __launch_bounds__(256) void spmm_quad_kernel(const unsigned short* __restrict__ X,
                                                        const int* __restrict__ off,
                                                        const int2* __restrict__ csr,
                                                        float* __restrict__ Y) {
    int wave = (int)((blockIdx.x * 256 + threadIdx.x) >> 6);
    int lane = threadIdx.x & 63;
    int q  = lane >> 4;
    int hl = lane & 15;
    int n = wave * 4 + q;
    if (n >= NN) return;
    int e0 = off[n];
    int e1 = off[n + 1];

    float acc[8] = {};
    for (int e = e0; e < e1; e += 8) {
        unsigned ssb[8];
        float    ww[8];
#pragma unroll
        for (int j = 0; j < 8; ++j) {
            int  ee = e + j;
            bool v  = ee < e1;
            int2 sw = csr[v ? ee : e0];
            ssb[j] = (unsigned)(sw.x * (FOUT * 2));   // 32-bit byte offset
            ww[j]  = v ? __int_as_float(sw.y) : 0.f;
        }
        u16x8 r[8];
#pragma unroll
        for (int j = 0; j < 8; ++j)
            r[j] = *(const u16x8*)((const char*)X + ssb[j] + hl * 16);
#pragma unroll
        for (int j = 0; j < 8; ++j)
#pragma unroll
            for (int k = 0; k < 8; ++k)
                acc[k] += ww[j] * bf2f(r[j][k]);
    }
    float4 o0 = make_float4(acc[0], acc[1], acc[2], acc[3]);
    float4 o1 = make_float4(acc[4], acc[5], acc[6], acc[7]);
    *(float4*)(Y + (size_t)n * FOUT + hl * 8) = o0;
    *(float4*)(Y + (size_t)n * FOUT + hl * 8 + 4) = o1;
}

// ---------------- launch ----------------

extern "C" void kernel_launch(void* const* d_in, const int* in_sizes, int n_in,
                              void* d_out, int out_size, void* d_ws, size_t ws_size,
                              hipStream_t stream) {
    const float* features = (const float*)d_in[0];
    const int*   edge_src = (const int*)d_in[1];
    const int*   edge_dst = (const int*)d_in[2];
    const float* edge_w   = (const float*)d_in[3];
    const float* W1       = (const float*)d_in[4];
    const float* W2       = (const float*)d_in[5];
    float* out = (float*)d_out;

    char*  ws  = (char*)d_ws;
    size_t ofs = 0;
    auto carve = [&](size_t bytes) -> void* {
        void* r = ws + ofs;
        ofs = (ofs + bytes + 255) & ~(size_t)255;
        return r;
    };
    int*            off   = (int*)carve((NN + 1) * sizeof(int));
    int*            bcur  = (int*)carve(NBKT * BSTRIDE * sizeof(int));
    int2*           barr  = (int2*)carve((size_t)NBKT * BCAP * sizeof(int2));
    int2*           csr   = (int2*)carve((size_t)NE * sizeof(int2));
    unsigned short* W1T   = (unsigned short*)carve((size_t)FHID * FIN * 2);
    unsigned short* W2T   = (unsigned short*)carve((size_t)FOUT * FHID * 2);
    unsigned short* H0b   = (unsigned short*)carve((size_t)MPAD * FHID * 2);
    unsigned short* H1b   = (unsigned short*)carve((size_t)MPAD * FOUT * 2);

    hipMemsetAsync(bcur, 0, NBKT * BSTRIDE * sizeof(int), stream);

    // k1: passA (bucket bin) || transpose W1 || transpose W2
    fused_passa_prep_kernel<<<PA_BLOCKS + TW1_BLOCKS + TW2_BLOCKS, 256, 0, stream>>>(
        edge_src, edge_dst, edge_w, bcur, barr, W1, W1T, W2, W2T);

    // k2: passB (off/csr) || gemm1 (H0 = X @ W1)
    fused_passb_gemm1_kernel<<<PB_BLOCKS + MPAD / 64, 256, 0, stream>>>(
        barr, bcur, off, csr, features, W1T, H0b);

    // k3': fused spmm1 (hidden tile in LDS, relu) + gemm2 -> H1  (1024 threads)
    fused_spmm1_gemm2_kernel<<<MPAD / 64, 1024, 0, stream>>>(H0b, off, csr, W2T, H1b);

    // k4: out = A @ H1
    spmm_quad_kernel<<<3125, 256, 0, stream>>>(H1b, off, csr, out);
}

// Round 17
// 169.580 us; speedup vs baseline: 1.0561x; 1.0561x over previous
//
#include <hip/hip_runtime.h>

#define NN 50000
#define NE 800000
#define FIN 512
#define FHID 256
#define FOUT 128
#define MPAD 50048  // 782 * 64

#define TW1_BLOCKS  512     // FIN*FHID/256
#define TW2_BLOCKS  128     // FHID*FOUT/256

// Two-level bucket sort
#define NBKT   196          // coarse bucket = dst >> 8
#define BCAP   5120         // slots/bucket: mean 4082 + 16 sigma
#define BSTRIDE 16          // bcur counter stride (ints) -> one 64B line each
#define PA_BLOCKS 392
#define E_CHA    2048       // 392 * 2048 = 802816 >= NE
#define PB_BLOCKS 196

using bf16x8 = __attribute__((ext_vector_type(8))) short;
using f32x4  = __attribute__((ext_vector_type(4))) float;
using u16x8  = __attribute__((ext_vector_type(8))) unsigned short;

__device__ __forceinline__ unsigned short f2bf(float f) {
    unsigned int u = __builtin_bit_cast(unsigned int, f);
    unsigned int r = (u + 0x7FFFu + ((u >> 16) & 1u)) >> 16;   // RNE
    return (unsigned short)r;
}
__device__ __forceinline__ float bf2f(unsigned short u) {
    return __builtin_bit_cast(float, (unsigned int)u << 16);
}
__device__ __forceinline__ void gload_lds16(const void* g, void* l) {
    __builtin_amdgcn_global_load_lds(
        (const __attribute__((address_space(1))) void*)g,
        (__attribute__((address_space(3))) void*)l, 16, 0, 0);
}

// ---- k1: passA (bucket bin) || transpose W1 || transpose W2 ----

__global__ __launch_bounds__(256) void fused_passa_prep_kernel(
    const int* __restrict__ src, const int* __restrict__ dst,
    const float* __restrict__ w, int* __restrict__ bcur, int2* __restrict__ barr,
    const float* __restrict__ W1, unsigned short* __restrict__ W1T,
    const float* __restrict__ W2, unsigned short* __restrict__ W2T) {
    int b = blockIdx.x, tid = threadIdx.x;
    if (b < PA_BLOCKS) {
        __shared__ int hist[NBKT];
        __shared__ int resv[NBKT];
        if (tid < NBKT) hist[tid] = 0;
        __syncthreads();
        int base = b * E_CHA + tid;
        int  d[8];
        bool m[8];
#pragma unroll
        for (int j = 0; j < 8; ++j) {
            int e = base + j * 256;
            m[j] = e < NE;
            d[j] = m[j] ? dst[e] : 0;
        }
#pragma unroll
        for (int j = 0; j < 8; ++j)
            if (m[j]) atomicAdd(&hist[d[j] >> 8], 1);
        __syncthreads();
        if (tid < NBKT) {
            int h = hist[tid];
            resv[tid] = (h > 0) ? atomicAdd(&bcur[tid * BSTRIDE], h) : 0;
            hist[tid] = 0;  // reuse as rank counter
        }
        __syncthreads();
        int   s[8];
        float wv[8];
#pragma unroll
        for (int j = 0; j < 8; ++j) {
            int e = base + j * 256;
            s[j]  = m[j] ? src[e] : 0;
            wv[j] = m[j] ? w[e] : 0.f;
        }
#pragma unroll
        for (int j = 0; j < 8; ++j) {
            if (m[j]) {
                int bb = d[j] >> 8;
                int r  = atomicAdd(&hist[bb], 1);
                int pos = resv[bb] + r;
                if (pos < BCAP)
                    barr[(size_t)bb * BCAP + pos] =
                        make_int2(s[j] | ((d[j] & 255) << 16), __float_as_int(wv[j]));
            }
        }
    } else if (b < PA_BLOCKS + TW1_BLOCKS) {
        int t = (b - PA_BLOCKS) * 256 + tid;
        int n = t % FHID, k = t / FHID;
        W1T[(size_t)n * FIN + k] = f2bf(W1[t]);
    } else {
        int t = (b - PA_BLOCKS - TW1_BLOCKS) * 256 + tid;
        int n = t % FOUT, k = t / FOUT;
        W2T[(size_t)n * FHID + k] = f2bf(W2[t]);
    }
}

// ---- GEMM1 body: 64x256 full-N tile, BK=64, direct f32 A (r14, unchanged) ----

__device__ __forceinline__ void gemm1_body(const float* __restrict__ X,
                                           const unsigned short* __restrict__ BT,
                                           unsigned short* __restrict__ C,
                                           int bx) {
    __shared__ unsigned short As[64 * 64];    // 8 KB
    __shared__ unsigned short Bs[256 * 64];   // 32 KB

    const int tid  = threadIdx.x;
    const int lane = tid & 63;
    const int wid  = tid >> 6;
    const int brow = bx * 64;
    const int r15   = lane & 15;
    const int khalf = (lane >> 4) * 8;

    const int arow0 = tid >> 3;
    const int arow1 = 32 + (tid >> 3);
    const int acol  = (tid & 7) * 8;
    const int g0 = min(brow + arow0, NN - 1);
    const int g1 = min(brow + arow1, NN - 1);
    const float4* ap0 = (const float4*)(X + (size_t)g0 * FIN + acol);
    const float4* ap1 = (const float4*)(X + (size_t)g1 * FIN + acol);
    const int ab0 = arow0 * 128 + ((acol * 2) ^ ((arow0 & 7) << 4));
    const int ab1 = arow1 * 128 + ((acol * 2) ^ ((arow1 & 7) << 4));

    f32x4 acc[4][4] = {};
    float4 a00 = ap0[0], a01 = ap0[1], a10 = ap1[0], a11 = ap1[1];

#pragma unroll
    for (int k = 0; k < 8; ++k) {
        const int k0 = k * 64;
#pragma unroll
        for (int c = 0; c < 8; ++c) {
            int b   = wid * 8192 + c * 1024 + lane * 16;
            int row = b >> 7;
            int cby = (b & 127) ^ ((row & 7) << 4);
            const char* gb = (const char*)(BT + (size_t)row * FIN + k0) + cby;
            gload_lds16(gb, (char*)Bs + wid * 8192 + c * 1024);
        }
        {
            u16x8 v;
            v[0] = f2bf(a00.x); v[1] = f2bf(a00.y); v[2] = f2bf(a00.z); v[3] = f2bf(a00.w);
            v[4] = f2bf(a01.x); v[5] = f2bf(a01.y); v[6] = f2bf(a01.z); v[7] = f2bf(a01.w);
            *(u16x8*)((char*)As + ab0) = v;
            v[0] = f2bf(a10.x); v[1] = f2bf(a10.y); v[2] = f2bf(a10.z); v[3] = f2bf(a10.w);
            v[4] = f2bf(a11.x); v[5] = f2bf(a11.y); v[6] = f2bf(a11.z); v[7] = f2bf(a11.w);
            *(u16x8*)((char*)As + ab1) = v;
        }
        __syncthreads();

        if (k < 7) {
            int q = (k0 + 64) >> 2;
            a00 = ap0[q]; a01 = ap0[q + 1]; a10 = ap1[q]; a11 = ap1[q + 1];
        }

        bf16x8 bfr[4][2];
#pragma unroll
        for (int n = 0; n < 4; ++n) {
            int row = wid * 64 + n * 16 + r15;
            int rb  = row * 128;
            int sw  = (row & 7) << 4;
#pragma unroll
            for (int ks = 0; ks < 2; ++ks)
                bfr[n][ks] = *(const bf16x8*)((const char*)Bs + rb + (((ks * 32 + khalf) * 2) ^ sw));
        }
#pragma unroll
        for (int m = 0; m < 4; ++m) {
            int row = m * 16 + r15;
            int rb  = row * 128;
            int sw  = (row & 7) << 4;
            bf16x8 af0 = *(const bf16x8*)((const char*)As + rb + (((0 + khalf) * 2) ^ sw));
            bf16x8 af1 = *(const bf16x8*)((const char*)As + rb + (((32 + khalf) * 2) ^ sw));
#pragma unroll
            for (int n = 0; n < 4; ++n) {
                acc[m][n] = __builtin_amdgcn_mfma_f32_16x16x32_bf16(af0, bfr[n][0], acc[m][n], 0, 0, 0);
                acc[m][n] = __builtin_amdgcn_mfma_f32_16x16x32_bf16(af1, bfr[n][1], acc[m][n], 0, 0, 0);
            }
        }
        __syncthreads();
    }

    const int rsub = (lane >> 4) * 4;
#pragma unroll
    for (int m = 0; m < 4; ++m) {
#pragma unroll
        for (int r = 0; r < 4; ++r) {
            int grow = brow + m * 16 + rsub + r;
            if (grow < NN) {
#pragma unroll
                for (int n = 0; n < 4; ++n)
                    C[(size_t)grow * FHID + wid * 64 + n * 16 + r15] = f2bf(acc[m][n][r]);
            }
        }
    }
}

// ---- passB body (self-scan, unchanged) ----

__device__ __forceinline__ void passb_body(const int2* __restrict__ barr,
                                           const int* __restrict__ bcur,
                                           int* __restrict__ off,
                                           int2* __restrict__ csr) {
    __shared__ int sc[256];
    __shared__ int cnt[256];
    __shared__ int pre[256];
    __shared__ int wsum[4];
    int b = blockIdx.x, tid = threadIdx.x, lane = tid & 63, wid = tid >> 6;

    int v = (tid < NBKT) ? min(bcur[tid * BSTRIDE], BCAP) : 0;
    int s = v;
#pragma unroll
    for (int d = 1; d < 64; d <<= 1) {
        int t = __shfl_up(s, d, 64);
        if (lane >= d) s += t;
    }
    if (lane == 63) wsum[wid] = s;
    __syncthreads();
    int wo = 0;
#pragma unroll
    for (int j = 0; j < 4; ++j)
        if (j < wid) wo += wsum[j];
    sc[tid] = wo + s - v;
    if (b == 0 && tid == NBKT - 1) off[NN] = wo + s;
    cnt[tid] = 0;
    __syncthreads();

    int bko_b = sc[b];
    int total = min(bcur[b * BSTRIDE], BCAP);
    const int2* seg = barr + (size_t)b * BCAP;

    for (int k = tid; k < total; k += 256)
        atomicAdd(&cnt[(seg[k].x >> 16) & 255], 1);
    __syncthreads();
    int v2 = cnt[tid];
    int s2 = v2;
#pragma unroll
    for (int d = 1; d < 64; d <<= 1) {
        int t = __shfl_up(s2, d, 64);
        if (lane >= d) s2 += t;
    }
    if (lane == 63) wsum[wid] = s2;
    __syncthreads();
    int wo2 = 0;
#pragma unroll
    for (int j = 0; j < 4; ++j)
        if (j < wid) wo2 += wsum[j];
    int base = bko_b + wo2 + s2 - v2;
    pre[tid] = base;
    int n = b * 256 + tid;
    if (n < NN) off[n] = base;
    cnt[tid] = 0;
    __syncthreads();
    for (int k = tid; k < total; k += 256) {
        int2 pl = seg[k];
        int dlow = (pl.x >> 16) & 255;
        int r = atomicAdd(&cnt[dlow], 1);
        csr[pre[dlow] + r] = make_int2(pl.x & 0xFFFF, pl.y);
    }
}

// ---- k2: passB || gemm1 ----

__global__ __launch_bounds__(256) void fused_passb_gemm1_kernel(
    const int2* __restrict__ barr, const int* __restrict__ bcur,
    int* __restrict__ off, int2* __restrict__ csr,
    const float* __restrict__ X, const unsigned short* __restrict__ BT,
    unsigned short* __restrict__ C) {
    if (blockIdx.x < PB_BLOCKS) {
        passb_body(barr, bcur, off, csr);
    } else {
        gemm1_body(X, BT, C, blockIdx.x - PB_BLOCKS);
    }
}

// ---- k3: pull-SpMM layer 1 (SPLIT, r14-proven): 2 nodes per wave, u16x8 loads ----

__global__ __launch_bounds__(256) void spmm_pair_kernel(const unsigned short* __restrict__ X,
                                                        const int* __restrict__ off,
                                                        const int2* __restrict__ csr,
                                                        unsigned short* __restrict__ Y) {
    int wave = (int)((blockIdx.x * 256 + threadIdx.x) >> 6);
    int lane = threadIdx.x & 63;
    int half = lane >> 5;
    int hl   = lane & 31;
    int n = wave * 2 + half;
    if (n >= NN) return;
    int e0 = off[n];
    int e1 = off[n + 1];

    float acc[8] = {};
    for (int e = e0; e < e1; e += 8) {
        unsigned ssb[8];
        float    ww[8];
#pragma unroll
        for (int j = 0; j < 8; ++j) {
            int  ee = e + j;
            bool v  = ee < e1;
            int2 sw = csr[v ? ee : e0];
            ssb[j] = (unsigned)(sw.x * (FHID * 2));   // 32-bit byte offset
            ww[j]  = v ? __int_as_float(sw.y) : 0.f;
        }
        u16x8 r[8];
#pragma unroll
        for (int j = 0; j < 8; ++j)
            r[j] = *(const u16x8*)((const char*)X + ssb[j] + hl * 16);
#pragma unroll
        for (int j = 0; j < 8; ++j)
#pragma unroll
            for (int k = 0; k < 8; ++k)
                acc[k] += ww[j] * bf2f(r[j][k]);
    }
    u16x8 o;
#pragma unroll
    for (int k = 0; k < 8; ++k) o[k] = f2bf(fmaxf(acc[k], 0.f));
    *(u16x8*)(Y + (size_t)n * FHID + (size_t)hl * 8) = o;
}

// ---- k4: GEMM2 standalone (r14-proven): 64x128 full-N tile, BK=64 ----

__global__ __launch_bounds__(256) void gemm2_kernel(const unsigned short* __restrict__ A,
                                                    const unsigned short* __restrict__ BT,
                                                    unsigned short* __restrict__ C) {
    __shared__ unsigned short As[64 * 64];    // 8 KB
    __shared__ unsigned short Bs[128 * 64];   // 16 KB

    const int tid  = threadIdx.x;
    const int lane = tid & 63;
    const int wid  = tid >> 6;
    const int brow = blockIdx.x * 64;
    const int r15   = lane & 15;
    const int khalf = (lane >> 4) * 8;

    f32x4 acc[4][2] = {};

#pragma unroll
    for (int k = 0; k < 4; ++k) {
        const int k0 = k * 64;
#pragma unroll
        for (int c = 0; c < 4; ++c) {
            int b   = wid * 4096 + c * 1024 + lane * 16;
            int row = b >> 7;
            int cby = (b & 127) ^ ((row & 7) << 4);
            const char* gb = (const char*)(BT + (size_t)row * FHID + k0) + cby;
            gload_lds16(gb, (char*)Bs + wid * 4096 + c * 1024);
        }
#pragma unroll
        for (int c = 0; c < 2; ++c) {
            int b   = wid * 2048 + c * 1024 + lane * 16;
            int row = b >> 7;
            int cby = (b & 127) ^ ((row & 7) << 4);
            const char* ga = (const char*)(A + (size_t)(brow + row) * FHID + k0) + cby;
            gload_lds16(ga, (char*)As + wid * 2048 + c * 1024);
        }
        __syncthreads();

        bf16x8 bfr[2][2];
#pragma unroll
        for (int n = 0; n < 2; ++n) {
            int row = wid * 32 + n * 16 + r15;
            int rb  = row * 128;
            int sw  = (row & 7) << 4;
#pragma unroll
            for (int ks = 0; ks < 2; ++ks)
                bfr[n][ks] = *(const bf16x8*)((const char*)Bs + rb + (((ks * 32 + khalf) * 2) ^ sw));
        }
#pragma unroll
        for (int m = 0; m < 4; ++m) {
            int row = m * 16 + r15;
            int rb  = row * 128;
            int sw  = (row & 7) << 4;
            bf16x8 af0 = *(const bf16x8*)((const char*)As + rb + (((0 + khalf) * 2) ^ sw));
            bf16x8 af1 = *(const bf16x8*)((const char*)As + rb + (((32 + khalf) * 2) ^ sw));
#pragma unroll
            for (int n = 0; n < 2; ++n) {
                acc[m][n] = __builtin_amdgcn_mfma_f32_16x16x32_bf16(af0, bfr[n][0], acc[m][n], 0, 0, 0);
                acc[m][n] = __builtin_amdgcn_mfma_f32_16x16x32_bf16(af1, bfr[n][1], acc[m][n], 0, 0, 0);
            }
        }
        __syncthreads();
    }

    const int rsub = (lane >> 4) * 4;
#pragma unroll
    for (int m = 0; m < 4; ++m) {
#pragma unroll
        for (int r = 0; r < 4; ++r) {
            int grow = brow + m * 16 + rsub + r;
            if (grow < NN) {
#pragma unroll
                for (int n = 0; n < 2; ++n)
                    C[(size_t)grow * FOUT + wid * 32 + n * 16 + r15] = f2bf(acc[m][n][r]);
            }
        }
    }
}

// ---- k5: pull-SpMM layer 2: 4 nodes per wave (16-lane quarters), f32 out ----

__global__ __launch_bounds__(256) void spmm_quad_kernel(const unsigned short* __restrict__ X,
                                                        const int* __restrict__ off,
                                                        const int2* __restrict__ csr,
                                                        float* __restrict__ Y) {
    int wave = (int)((blockIdx.x * 256 + threadIdx.x) >> 6);
    int lane = threadIdx.x & 63;
    int q  = lane >> 4;
    int hl = lane & 15;
    int n = wave * 4 + q;
    if (n >= NN) return;
    int e0 = off[n];
    int e1 = off[n + 1];

    float acc[8] = {};
    for (int e = e0; e < e1; e += 8) {
        unsigned ssb[8];
        float    ww[8];
#pragma unroll
        for (int j = 0; j < 8; ++j) {
            int  ee = e + j;
            bool v  = ee < e1;
            int2 sw = csr[v ? ee : e0];
            ssb[j] = (unsigned)(sw.x * (FOUT * 2));   // 32-bit byte offset
            ww[j]  = v ? __int_as_float(sw.y) : 0.f;
        }
        u16x8 r[8];
#pragma unroll
        for (int j = 0; j < 8; ++j)
            r[j] = *(const u16x8*)((const char*)X + ssb[j] + hl * 16);
#pragma unroll
        for (int j = 0; j < 8; ++j)
#pragma unroll
            for (int k = 0; k < 8; ++k)
                acc[k] += ww[j] * bf2f(r[j][k]);
    }
    float4 o0 = make_float4(acc[0], acc[1], acc[2], acc[3]);
    float4 o1 = make_float4(acc[4], acc[5], acc[6], acc[7]);
    *(float4*)(Y + (size_t)n * FOUT + hl * 8) = o0;
    *(float4*)(Y + (size_t)n * FOUT + hl * 8 + 4) = o1;
}

// ---------------- launch ----------------

extern "C" void kernel_launch(void* const* d_in, const int* in_sizes, int n_in,
                              void* d_out, int out_size, void* d_ws, size_t ws_size,
                              hipStream_t stream) {
    const float* features = (const float*)d_in[0];
    const int*   edge_src = (const int*)d_in[1];
    const int*   edge_dst = (const int*)d_in[2];
    const float* edge_w   = (const float*)d_in[3];
    const float* W1       = (const float*)d_in[4];
    const float* W2       = (const float*)d_in[5];
    float* out = (float*)d_out;

    char*  ws  = (char*)d_ws;
    size_t ofs = 0;
    auto carve = [&](size_t bytes) -> void* {
        void* r = ws + ofs;
        ofs = (ofs + bytes + 255) & ~(size_t)255;
        return r;
    };
    int*            off   = (int*)carve((NN + 1) * sizeof(int));
    int*            bcur  = (int*)carve(NBKT * BSTRIDE * sizeof(int));
    int2*           barr  = (int2*)carve((size_t)NBKT * BCAP * sizeof(int2));
    int2*           csr   = (int2*)carve((size_t)NE * sizeof(int2));
    unsigned short* W1T   = (unsigned short*)carve((size_t)FHID * FIN * 2);
    unsigned short* W2T   = (unsigned short*)carve((size_t)FOUT * FHID * 2);
    unsigned short* H0b   = (unsigned short*)carve((size_t)MPAD * FHID * 2);
    unsigned short* Hb    = (unsigned short*)carve((size_t)MPAD * FHID * 2);
    unsigned short* H1b   = H0b;  // H0b dead after spmm1

    hipMemsetAsync(bcur, 0, NBKT * BSTRIDE * sizeof(int), stream);

    // k1: passA (bucket bin) || transpose W1 || transpose W2
    fused_passa_prep_kernel<<<PA_BLOCKS + TW1_BLOCKS + TW2_BLOCKS, 256, 0, stream>>>(
        edge_src, edge_dst, edge_w, bcur, barr, W1, W1T, W2, W2T);

    // k2: passB (off/csr) || gemm1 (H0 = X @ W1)
    fused_passb_gemm1_kernel<<<PB_BLOCKS + MPAD / 64, 256, 0, stream>>>(
        barr, bcur, off, csr, features, W1T, H0b);

    // k3: hidden = relu(A @ H0)  (bf16) — 2 nodes/wave, split (max gather TLP)
    spmm_pair_kernel<<<6250, 256, 0, stream>>>(H0b, off, csr, Hb);

    // k4: H1 = hidden @ W2 (64x128 full-N)
    gemm2_kernel<<<MPAD / 64, 256, 0, stream>>>(Hb, W2T, H1b);

    // k5: out = A @ H1 — 4 nodes/wave
    spmm_quad_kernel<<<3125, 256, 0, stream>>>(H1b, off, csr, out);
}